// Round 3
// baseline (1367.044 us; speedup 1.0000x reference)
//
#include <hip/hip_runtime.h>

#define N_NODES 100000
#define N_EDGES 1600000
#define D 64
#define N_LAYERS 5
#define SCAN_BLOCKS 391   // ceil(N_NODES / 256)

// ============================ CSR build (once per launch) ====================

__global__ __launch_bounds__(256) void hist_kernel(
    const int* __restrict__ dst, int* __restrict__ counts)
{
    int e = blockIdx.x * 256 + threadIdx.x;
    if (e < N_EDGES) atomicAdd(&counts[dst[e]], 1);
}

// Phase A: per-block sums of counts (coalesced).
__global__ __launch_bounds__(256) void scan_bsum_kernel(
    const int* __restrict__ counts, int* __restrict__ bsum)
{
    __shared__ int red[256];
    int t = threadIdx.x;
    int i = blockIdx.x * 256 + t;
    red[t] = (i < N_NODES) ? counts[i] : 0;
    __syncthreads();
    for (int off = 128; off > 0; off >>= 1) {
        if (t < off) red[t] += red[t + off];
        __syncthreads();
    }
    if (t == 0) bsum[blockIdx.x] = red[0];
}

// Phase B: single block scans the 391 block sums (exclusive), writes total.
__global__ __launch_bounds__(512) void scan_bscan_kernel(
    const int* __restrict__ bsum, int* __restrict__ bscan,
    int* __restrict__ rowptr)
{
    __shared__ int s[512];
    int t = threadIdx.x;
    int v = (t < SCAN_BLOCKS) ? bsum[t] : 0;
    s[t] = v;
    __syncthreads();
    for (int off = 1; off < 512; off <<= 1) {
        int u = (t >= off) ? s[t - off] : 0;
        __syncthreads();
        s[t] += u;
        __syncthreads();
    }
    if (t < SCAN_BLOCKS) bscan[t] = s[t] - v;   // exclusive prefix
    if (t == 511) rowptr[N_NODES] = s[511];     // total = N_EDGES
}

// Phase C: local inclusive scan per block + block offset -> rowptr & cursor.
__global__ __launch_bounds__(256) void scan_final_kernel(
    const int* __restrict__ counts, const int* __restrict__ bscan,
    int* __restrict__ rowptr, int* __restrict__ cursor)
{
    __shared__ int s[256];
    int t = threadIdx.x;
    int i = blockIdx.x * 256 + t;
    int v = (i < N_NODES) ? counts[i] : 0;
    s[t] = v;
    __syncthreads();
    for (int off = 1; off < 256; off <<= 1) {
        int u = (t >= off) ? s[t - off] : 0;
        __syncthreads();
        s[t] += u;
        __syncthreads();
    }
    if (i < N_NODES) {
        int excl = s[t] - v + bscan[blockIdx.x];
        rowptr[i] = excl;
        cursor[i] = excl;
    }
}

__global__ __launch_bounds__(256) void place_kernel(
    const int* __restrict__ src, const int* __restrict__ dst,
    const float* __restrict__ ew, int* __restrict__ cursor,
    int* __restrict__ sorted_src, float* __restrict__ sorted_w)
{
    int e = blockIdx.x * 256 + threadIdx.x;
    if (e >= N_EDGES) return;
    int d = dst[e];
    int p = atomicAdd(&cursor[d], 1);
    sorted_src[p] = src[e];
    sorted_w[p] = ew[e];
}

// ==================== Fused layer: aggregate + dense update ==================
// Block = 512 threads = 8 waves = 32 nodes. Wave g aggregates nodes g*4..g*4+3
// (lane = dim, register acc -> LDS), then matmul phase: float4 BROADCAST reads
// of sA/sX rows (wave-uniform addr) + conflict-free b32 weight column reads.
__global__ __launch_bounds__(512) void layer_kernel(
    const float* __restrict__ hin, const int* __restrict__ rowptr,
    const int* __restrict__ ssrc, const float* __restrict__ sw,
    const float* __restrict__ Wrel, const float* __restrict__ brel,
    const float* __restrict__ Wroot, float* __restrict__ hout, int relu)
{
    __shared__ float sWrel[64 * 64];    // 16 KB
    __shared__ float sWroot[64 * 64];   // 16 KB
    __shared__ float sb[64];
    __shared__ float sA[32][64];        // 8 KB  aggregated messages
    __shared__ float sX[32][64];        // 8 KB  own features

    const int t = threadIdx.x;
    const int nbase = blockIdx.x * 32;

    for (int i = t; i < 64 * 64; i += 512) {
        sWrel[i]  = Wrel[i];
        sWroot[i] = Wroot[i];
    }
    if (t < 64) sb[t] = brel[t];
    for (int i = t; i < 32 * 64; i += 512) {
        int ln = i >> 6, dd = i & 63;
        int n = nbase + ln;
        sX[ln][dd] = (n < N_NODES) ? hin[(size_t)n * D + dd] : 0.f;
    }

    const int g = t >> 6;        // wave 0..7
    const int lane = t & 63;     // feature dim

    // ---- aggregation: wave g computes sA rows g*4 .. g*4+3 ----
    for (int j = 0; j < 4; ++j) {
        int ln = g * 4 + j;
        int node = nbase + ln;
        float acc = 0.f;
        if (node < N_NODES) {
            int b = rowptr[node];
            int e = rowptr[node + 1];
            int i = b;
            for (; i + 1 < e; i += 2) {
                int s0 = ssrc[i], s1 = ssrc[i + 1];
                float w0 = sw[i], w1 = sw[i + 1];
                acc += hin[(size_t)s0 * D + lane] * w0
                     + hin[(size_t)s1 * D + lane] * w1;
            }
            if (i < e) acc += hin[(size_t)ssrc[i] * D + lane] * sw[i];
        }
        sA[ln][lane] = acc;
    }
    __syncthreads();

    // ---- matmul: thread (g, d=lane) computes 4 nodes' dim d ----
    const int d = lane;
    const float4* A0 = (const float4*)sA[g * 4 + 0];
    const float4* A1 = (const float4*)sA[g * 4 + 1];
    const float4* A2 = (const float4*)sA[g * 4 + 2];
    const float4* A3 = (const float4*)sA[g * 4 + 3];
    const float4* X0 = (const float4*)sX[g * 4 + 0];
    const float4* X1 = (const float4*)sX[g * 4 + 1];
    const float4* X2 = (const float4*)sX[g * 4 + 2];
    const float4* X3 = (const float4*)sX[g * 4 + 3];

    float acc0 = sb[d], acc1 = sb[d], acc2 = sb[d], acc3 = sb[d];
    #pragma unroll 4
    for (int k4 = 0; k4 < 16; ++k4) {
        float4 a0 = A0[k4], a1 = A1[k4], a2 = A2[k4], a3 = A3[k4];
        float4 x0 = X0[k4], x1 = X1[k4], x2 = X2[k4], x3 = X3[k4];
        int k = k4 * 4;
        float wr0 = sWrel[(k + 0) * 64 + d];
        float wr1 = sWrel[(k + 1) * 64 + d];
        float wr2 = sWrel[(k + 2) * 64 + d];
        float wr3 = sWrel[(k + 3) * 64 + d];
        float wo0 = sWroot[(k + 0) * 64 + d];
        float wo1 = sWroot[(k + 1) * 64 + d];
        float wo2 = sWroot[(k + 2) * 64 + d];
        float wo3 = sWroot[(k + 3) * 64 + d];
        acc0 += a0.x*wr0 + a0.y*wr1 + a0.z*wr2 + a0.w*wr3
              + x0.x*wo0 + x0.y*wo1 + x0.z*wo2 + x0.w*wo3;
        acc1 += a1.x*wr0 + a1.y*wr1 + a1.z*wr2 + a1.w*wr3
              + x1.x*wo0 + x1.y*wo1 + x1.z*wo2 + x1.w*wo3;
        acc2 += a2.x*wr0 + a2.y*wr1 + a2.z*wr2 + a2.w*wr3
              + x2.x*wo0 + x2.y*wo1 + x2.z*wo2 + x2.w*wo3;
        acc3 += a3.x*wr0 + a3.y*wr1 + a3.z*wr2 + a3.w*wr3
              + x3.x*wo0 + x3.y*wo1 + x3.z*wo2 + x3.w*wo3;
    }
    if (relu) {
        acc0 = fmaxf(acc0, 0.f);
        acc1 = fmaxf(acc1, 0.f);
        acc2 = fmaxf(acc2, 0.f);
        acc3 = fmaxf(acc3, 0.f);
    }
    int n0 = nbase + g * 4;
    if (n0 + 0 < N_NODES) hout[(size_t)(n0 + 0) * D + d] = acc0;
    if (n0 + 1 < N_NODES) hout[(size_t)(n0 + 1) * D + d] = acc1;
    if (n0 + 2 < N_NODES) hout[(size_t)(n0 + 2) * D + d] = acc2;
    if (n0 + 3 < N_NODES) hout[(size_t)(n0 + 3) * D + d] = acc3;
}

extern "C" void kernel_launch(void* const* d_in, const int* in_sizes, int n_in,
                              void* d_out, int out_size, void* d_ws, size_t ws_size,
                              hipStream_t stream)
{
    const float* x     = (const float*)d_in[0];
    const int*   ei    = (const int*)d_in[1];   // [2, E] int32
    const float* ew    = (const float*)d_in[2];
    const float* Wrel  = (const float*)d_in[3]; // [5, 64, 64]
    const float* brel  = (const float*)d_in[4]; // [5, 64]
    const float* Wroot = (const float*)d_in[5]; // [5, 64, 64]
    float* out = (float*)d_out;

    const int* src = ei;
    const int* dst = ei + N_EDGES;

    const size_t feat_bytes = (size_t)N_NODES * D * sizeof(float); // 25.6 MB
    char* ws = (char*)d_ws;
    size_t off = 0;
    float* bufA       = (float*)(ws + off); off += feat_bytes;
    float* bufB       = (float*)(ws + off); off += feat_bytes;
    int*   counts     = (int*)(ws + off);   off += 400000;
    int*   cursor     = (int*)(ws + off);   off += 400000;
    int*   rowptr     = (int*)(ws + off);   off += 400016;
    int*   bsum       = (int*)(ws + off);   off += 2048;
    int*   bscan      = (int*)(ws + off);   off += 2048;
    int*   sorted_src = (int*)(ws + off);   off += (size_t)N_EDGES * 4;
    float* sorted_w   = (float*)(ws + off); off += (size_t)N_EDGES * 4;

    const int eblocks = (N_EDGES + 255) / 256;   // 6250
    const int lblocks = (N_NODES + 31) / 32;     // 3125

    // ---- CSR build ----
    hipMemsetAsync(counts, 0, N_NODES * sizeof(int), stream);
    hist_kernel<<<eblocks, 256, 0, stream>>>(dst, counts);
    scan_bsum_kernel<<<SCAN_BLOCKS, 256, 0, stream>>>(counts, bsum);
    scan_bscan_kernel<<<1, 512, 0, stream>>>(bsum, bscan, rowptr);
    scan_final_kernel<<<SCAN_BLOCKS, 256, 0, stream>>>(counts, bscan,
                                                       rowptr, cursor);
    place_kernel<<<eblocks, 256, 0, stream>>>(src, dst, ew, cursor,
                                              sorted_src, sorted_w);

    // ---- 5 fused GraphConv layers (ping-pong: gather races forbid in-place)
    const float* hin = x;
    for (int layer = 0; layer < N_LAYERS; ++layer) {
        float* hout = (layer == N_LAYERS - 1) ? out
                      : ((layer & 1) ? bufB : bufA);
        layer_kernel<<<lblocks, 512, 0, stream>>>(
            hin, rowptr, sorted_src, sorted_w,
            Wrel + (size_t)layer * D * D, brel + (size_t)layer * D,
            Wroot + (size_t)layer * D * D, hout,
            (layer < N_LAYERS - 1) ? 1 : 0);
        hin = hout;
    }
}

// Round 4
// 854.694 us; speedup vs baseline: 1.5995x; 1.5995x over previous
//
#include <hip/hip_runtime.h>

#define N_NODES 100000
#define N_EDGES 1600000
#define D 64
#define N_LAYERS 5
#define SCAN_BLOCKS 391   // ceil(N_NODES / 256)

// ============================ CSR build (once per launch) ====================

__global__ __launch_bounds__(256) void hist_kernel(
    const int* __restrict__ dst, int* __restrict__ counts)
{
    int e = blockIdx.x * 256 + threadIdx.x;
    if (e < N_EDGES) atomicAdd(&counts[dst[e]], 1);
}

__global__ __launch_bounds__(256) void scan_bsum_kernel(
    const int* __restrict__ counts, int* __restrict__ bsum)
{
    __shared__ int red[256];
    int t = threadIdx.x;
    int i = blockIdx.x * 256 + t;
    red[t] = (i < N_NODES) ? counts[i] : 0;
    __syncthreads();
    for (int off = 128; off > 0; off >>= 1) {
        if (t < off) red[t] += red[t + off];
        __syncthreads();
    }
    if (t == 0) bsum[blockIdx.x] = red[0];
}

__global__ __launch_bounds__(512) void scan_bscan_kernel(
    const int* __restrict__ bsum, int* __restrict__ bscan,
    int* __restrict__ rowptr)
{
    __shared__ int s[512];
    int t = threadIdx.x;
    int v = (t < SCAN_BLOCKS) ? bsum[t] : 0;
    s[t] = v;
    __syncthreads();
    for (int off = 1; off < 512; off <<= 1) {
        int u = (t >= off) ? s[t - off] : 0;
        __syncthreads();
        s[t] += u;
        __syncthreads();
    }
    if (t < SCAN_BLOCKS) bscan[t] = s[t] - v;
    if (t == 511) rowptr[N_NODES] = s[511];
}

__global__ __launch_bounds__(256) void scan_final_kernel(
    const int* __restrict__ counts, const int* __restrict__ bscan,
    int* __restrict__ rowptr, int* __restrict__ cursor)
{
    __shared__ int s[256];
    int t = threadIdx.x;
    int i = blockIdx.x * 256 + t;
    int v = (i < N_NODES) ? counts[i] : 0;
    s[t] = v;
    __syncthreads();
    for (int off = 1; off < 256; off <<= 1) {
        int u = (t >= off) ? s[t - off] : 0;
        __syncthreads();
        s[t] += u;
        __syncthreads();
    }
    if (i < N_NODES) {
        int excl = s[t] - v + bscan[blockIdx.x];
        rowptr[i] = excl;
        cursor[i] = excl;
    }
}

__global__ __launch_bounds__(256) void place_kernel(
    const int* __restrict__ src, const int* __restrict__ dst,
    const float* __restrict__ ew, int* __restrict__ cursor,
    int* __restrict__ sorted_src, float* __restrict__ sorted_w)
{
    int e = blockIdx.x * 256 + threadIdx.x;
    if (e >= N_EDGES) return;
    int d = dst[e];
    int p = atomicAdd(&cursor[d], 1);
    sorted_src[p] = src[e];
    sorted_w[p] = ew[e];
}

// ==================== Aggregation: node-per-wave, 8-deep MLP =================
// Lane j cooperatively loads edge (b+j) index/weight in ONE coalesced load,
// broadcasts via __shfl; row gathers unrolled 8x -> 8 independent 256B loads
// in flight per wave. Tiny LDS/VGPR footprint -> full occupancy.
__global__ __launch_bounds__(256) void agg_kernel(
    const float* __restrict__ h, const int* __restrict__ rowptr,
    const int* __restrict__ ssrc, const float* __restrict__ sw,
    float* __restrict__ agg)
{
    int node = (blockIdx.x * 256 + threadIdx.x) >> 6;
    int lane = threadIdx.x & 63;
    if (node >= N_NODES) return;
    int b = rowptr[node];
    int e = rowptr[node + 1];
    float acc = 0.f;
    for (int base = b; base < e; base += 64) {
        int cnt = min(64, e - base);
        int idx = 0;
        float wv = 0.f;
        if (lane < cnt) {
            idx = ssrc[base + lane];
            wv  = sw[base + lane];
        }
        int j = 0;
        for (; j + 8 <= cnt; j += 8) {
            int s0 = __shfl(idx, j + 0), s1 = __shfl(idx, j + 1);
            int s2 = __shfl(idx, j + 2), s3 = __shfl(idx, j + 3);
            int s4 = __shfl(idx, j + 4), s5 = __shfl(idx, j + 5);
            int s6 = __shfl(idx, j + 6), s7 = __shfl(idx, j + 7);
            float w0 = __shfl(wv, j + 0), w1 = __shfl(wv, j + 1);
            float w2 = __shfl(wv, j + 2), w3 = __shfl(wv, j + 3);
            float w4 = __shfl(wv, j + 4), w5 = __shfl(wv, j + 5);
            float w6 = __shfl(wv, j + 6), w7 = __shfl(wv, j + 7);
            float v0 = h[(size_t)s0 * D + lane];
            float v1 = h[(size_t)s1 * D + lane];
            float v2 = h[(size_t)s2 * D + lane];
            float v3 = h[(size_t)s3 * D + lane];
            float v4 = h[(size_t)s4 * D + lane];
            float v5 = h[(size_t)s5 * D + lane];
            float v6 = h[(size_t)s6 * D + lane];
            float v7 = h[(size_t)s7 * D + lane];
            acc += v0 * w0 + v1 * w1 + v2 * w2 + v3 * w3
                 + v4 * w4 + v5 * w5 + v6 * w6 + v7 * w7;
        }
        for (; j < cnt; ++j) {
            int s = __shfl(idx, j);
            float w = __shfl(wv, j);
            acc += h[(size_t)s * D + lane] * w;
        }
    }
    agg[(size_t)node * D + lane] = acc;
}

// ==================== Dense update: 8 nodes per thread =======================
// Block = 256 threads = 4 waves = 32 nodes; wave g computes nodes g*8..g*8+7.
// Weight column reads amortized over 8 nodes; sA/sX rows read as float4
// wave-uniform broadcasts.
__global__ __launch_bounds__(256) void update_kernel(
    const float* __restrict__ hin, const float* __restrict__ agg,
    const float* __restrict__ Wrel, const float* __restrict__ brel,
    const float* __restrict__ Wroot, float* __restrict__ hout, int relu)
{
    __shared__ float sWrel[64 * 64];   // 16 KB
    __shared__ float sWroot[64 * 64];  // 16 KB
    __shared__ float sA[32][64];       // 8 KB
    __shared__ float sX[32][64];       // 8 KB

    const int t = threadIdx.x;
    const int nbase = blockIdx.x * 32;

    for (int i = t; i < 64 * 64; i += 256) {
        sWrel[i]  = Wrel[i];
        sWroot[i] = Wroot[i];
    }
    for (int i = t; i < 32 * 64; i += 256) {
        int ln = i >> 6, dd = i & 63;
        int n = nbase + ln;
        float a = 0.f, xx = 0.f;
        if (n < N_NODES) {
            a  = agg[(size_t)n * D + dd];
            xx = hin[(size_t)n * D + dd];
        }
        sA[ln][dd] = a;
        sX[ln][dd] = xx;
    }
    __syncthreads();

    const int d = t & 63;
    const int g = t >> 6;   // wave 0..3 -> nodes g*8 .. g*8+7
    float bias = brel[d];
    float acc[8];
    #pragma unroll
    for (int j = 0; j < 8; ++j) acc[j] = bias;

    #pragma unroll 4
    for (int k4 = 0; k4 < 16; ++k4) {
        int k = k4 * 4;
        float wr0 = sWrel[(k + 0) * 64 + d];
        float wr1 = sWrel[(k + 1) * 64 + d];
        float wr2 = sWrel[(k + 2) * 64 + d];
        float wr3 = sWrel[(k + 3) * 64 + d];
        float wo0 = sWroot[(k + 0) * 64 + d];
        float wo1 = sWroot[(k + 1) * 64 + d];
        float wo2 = sWroot[(k + 2) * 64 + d];
        float wo3 = sWroot[(k + 3) * 64 + d];
        #pragma unroll
        for (int j = 0; j < 8; ++j) {
            float4 a  = ((const float4*)sA[g * 8 + j])[k4];
            float4 xv = ((const float4*)sX[g * 8 + j])[k4];
            acc[j] += a.x * wr0 + a.y * wr1 + a.z * wr2 + a.w * wr3
                    + xv.x * wo0 + xv.y * wo1 + xv.z * wo2 + xv.w * wo3;
        }
    }

    #pragma unroll
    for (int j = 0; j < 8; ++j) {
        float v = relu ? fmaxf(acc[j], 0.f) : acc[j];
        int n = nbase + g * 8 + j;
        if (n < N_NODES) hout[(size_t)n * D + d] = v;
    }
}

extern "C" void kernel_launch(void* const* d_in, const int* in_sizes, int n_in,
                              void* d_out, int out_size, void* d_ws, size_t ws_size,
                              hipStream_t stream)
{
    const float* x     = (const float*)d_in[0];
    const int*   ei    = (const int*)d_in[1];   // [2, E] int32
    const float* ew    = (const float*)d_in[2];
    const float* Wrel  = (const float*)d_in[3]; // [5, 64, 64]
    const float* brel  = (const float*)d_in[4]; // [5, 64]
    const float* Wroot = (const float*)d_in[5]; // [5, 64, 64]
    float* out = (float*)d_out;

    const int* src = ei;
    const int* dst = ei + N_EDGES;

    const size_t feat_bytes = (size_t)N_NODES * D * sizeof(float); // 25.6 MB
    char* ws = (char*)d_ws;
    size_t off = 0;
    float* agg        = (float*)(ws + off); off += feat_bytes;
    float* hbuf       = (float*)(ws + off); off += feat_bytes;
    int*   counts     = (int*)(ws + off);   off += 400000;
    int*   cursor     = (int*)(ws + off);   off += 400000;
    int*   rowptr     = (int*)(ws + off);   off += 400016;
    int*   bsum       = (int*)(ws + off);   off += 2048;
    int*   bscan      = (int*)(ws + off);   off += 2048;
    int*   sorted_src = (int*)(ws + off);   off += (size_t)N_EDGES * 4;
    float* sorted_w   = (float*)(ws + off); off += (size_t)N_EDGES * 4;

    const int eblocks = (N_EDGES + 255) / 256;       // 6250
    const int ablocks = (N_NODES * 64 + 255) / 256;  // 25000 (wave per node)
    const int ublocks = (N_NODES + 31) / 32;         // 3125

    // ---- CSR build ----
    hipMemsetAsync(counts, 0, N_NODES * sizeof(int), stream);
    hist_kernel<<<eblocks, 256, 0, stream>>>(dst, counts);
    scan_bsum_kernel<<<SCAN_BLOCKS, 256, 0, stream>>>(counts, bsum);
    scan_bscan_kernel<<<1, 512, 0, stream>>>(bsum, bscan, rowptr);
    scan_final_kernel<<<SCAN_BLOCKS, 256, 0, stream>>>(counts, bscan,
                                                       rowptr, cursor);
    place_kernel<<<eblocks, 256, 0, stream>>>(src, dst, ew, cursor,
                                              sorted_src, sorted_w);

    // ---- 5 GraphConv layers ----
    const float* hin = x;
    for (int layer = 0; layer < N_LAYERS; ++layer) {
        agg_kernel<<<ablocks, 256, 0, stream>>>(hin, rowptr, sorted_src,
                                                sorted_w, agg);
        float* hout = (layer == N_LAYERS - 1) ? out : hbuf;
        update_kernel<<<ublocks, 256, 0, stream>>>(
            hin, agg, Wrel + (size_t)layer * D * D, brel + (size_t)layer * D,
            Wroot + (size_t)layer * D * D, hout,
            (layer < N_LAYERS - 1) ? 1 : 0);
        hin = hout;  // update is block-local -> in-place safe on hbuf
    }
}

// Round 5
// 775.062 us; speedup vs baseline: 1.7638x; 1.1027x over previous
//
#include <hip/hip_runtime.h>

#define N_NODES 100000
#define N_EDGES 1600000
#define D 64
#define N_LAYERS 5
#define SCAN_BLOCKS 391   // ceil(N_NODES / 256)

typedef unsigned short u16;

__device__ __forceinline__ float bf2f(u16 u) {
    union { unsigned int i; float f; } v;
    v.i = ((unsigned int)u) << 16;
    return v.f;
}
__device__ __forceinline__ u16 f2bf(float f) {
    union { float f; unsigned int i; } v;
    v.f = f;
    unsigned int r = v.i + 0x7FFFu + ((v.i >> 16) & 1u);  // round-nearest-even
    return (u16)(r >> 16);
}

// ============================ CSR build (once per launch) ====================

__global__ __launch_bounds__(256) void hist_kernel(
    const int* __restrict__ dst, int* __restrict__ counts)
{
    int e = blockIdx.x * 256 + threadIdx.x;
    if (e < N_EDGES) atomicAdd(&counts[dst[e]], 1);
}

__global__ __launch_bounds__(256) void scan_bsum_kernel(
    const int* __restrict__ counts, int* __restrict__ bsum)
{
    __shared__ int red[256];
    int t = threadIdx.x;
    int i = blockIdx.x * 256 + t;
    red[t] = (i < N_NODES) ? counts[i] : 0;
    __syncthreads();
    for (int off = 128; off > 0; off >>= 1) {
        if (t < off) red[t] += red[t + off];
        __syncthreads();
    }
    if (t == 0) bsum[blockIdx.x] = red[0];
}

__global__ __launch_bounds__(512) void scan_bscan_kernel(
    const int* __restrict__ bsum, int* __restrict__ bscan,
    int* __restrict__ rowptr)
{
    __shared__ int s[512];
    int t = threadIdx.x;
    int v = (t < SCAN_BLOCKS) ? bsum[t] : 0;
    s[t] = v;
    __syncthreads();
    for (int off = 1; off < 512; off <<= 1) {
        int u = (t >= off) ? s[t - off] : 0;
        __syncthreads();
        s[t] += u;
        __syncthreads();
    }
    if (t < SCAN_BLOCKS) bscan[t] = s[t] - v;
    if (t == 511) rowptr[N_NODES] = s[511];
}

__global__ __launch_bounds__(256) void scan_final_kernel(
    const int* __restrict__ counts, const int* __restrict__ bscan,
    int* __restrict__ rowptr, int* __restrict__ cursor)
{
    __shared__ int s[256];
    int t = threadIdx.x;
    int i = blockIdx.x * 256 + t;
    int v = (i < N_NODES) ? counts[i] : 0;
    s[t] = v;
    __syncthreads();
    for (int off = 1; off < 256; off <<= 1) {
        int u = (t >= off) ? s[t - off] : 0;
        __syncthreads();
        s[t] += u;
        __syncthreads();
    }
    if (i < N_NODES) {
        int excl = s[t] - v + bscan[blockIdx.x];
        rowptr[i] = excl;
        cursor[i] = excl;
    }
}

// One 8B packed store per edge (src, w) instead of two 4B stores.
__global__ __launch_bounds__(256) void place_kernel(
    const int* __restrict__ src, const int* __restrict__ dst,
    const float* __restrict__ ew, int* __restrict__ cursor,
    int2* __restrict__ edges)
{
    int e = blockIdx.x * 256 + threadIdx.x;
    if (e >= N_EDGES) return;
    int d = dst[e];
    int p = atomicAdd(&cursor[d], 1);
    edges[p] = make_int2(src[e], __float_as_int(ew[e]));
}

// ======================= f32 -> bf16 convert (input x) =======================
__global__ __launch_bounds__(256) void f2bf_kernel(
    const float* __restrict__ in, u16* __restrict__ out)
{
    int i = blockIdx.x * 256 + threadIdx.x;   // one float4 per thread
    if (i >= (N_NODES * D) / 4) return;
    float4 v = ((const float4*)in)[i];
    ushort4 o;
    o.x = f2bf(v.x); o.y = f2bf(v.y); o.z = f2bf(v.z); o.w = f2bf(v.w);
    ((ushort4*)out)[i] = o;
}

// ==================== Aggregation: node-per-wave, 8-deep MLP, bf16 ===========
__global__ __launch_bounds__(256) void agg_kernel(
    const u16* __restrict__ h, const int* __restrict__ rowptr,
    const int2* __restrict__ edges, u16* __restrict__ agg)
{
    int node = (blockIdx.x * 256 + threadIdx.x) >> 6;
    int lane = threadIdx.x & 63;
    if (node >= N_NODES) return;
    int b = rowptr[node];
    int e = rowptr[node + 1];
    float acc = 0.f;
    for (int base = b; base < e; base += 64) {
        int cnt = min(64, e - base);
        int idx = 0;
        float wv = 0.f;
        if (lane < cnt) {
            int2 p = edges[base + lane];     // one coalesced 8B load
            idx = p.x;
            wv = __int_as_float(p.y);
        }
        int j = 0;
        for (; j + 8 <= cnt; j += 8) {
            int s0 = __shfl(idx, j + 0), s1 = __shfl(idx, j + 1);
            int s2 = __shfl(idx, j + 2), s3 = __shfl(idx, j + 3);
            int s4 = __shfl(idx, j + 4), s5 = __shfl(idx, j + 5);
            int s6 = __shfl(idx, j + 6), s7 = __shfl(idx, j + 7);
            float w0 = __shfl(wv, j + 0), w1 = __shfl(wv, j + 1);
            float w2 = __shfl(wv, j + 2), w3 = __shfl(wv, j + 3);
            float w4 = __shfl(wv, j + 4), w5 = __shfl(wv, j + 5);
            float w6 = __shfl(wv, j + 6), w7 = __shfl(wv, j + 7);
            float v0 = bf2f(h[(size_t)s0 * D + lane]);
            float v1 = bf2f(h[(size_t)s1 * D + lane]);
            float v2 = bf2f(h[(size_t)s2 * D + lane]);
            float v3 = bf2f(h[(size_t)s3 * D + lane]);
            float v4 = bf2f(h[(size_t)s4 * D + lane]);
            float v5 = bf2f(h[(size_t)s5 * D + lane]);
            float v6 = bf2f(h[(size_t)s6 * D + lane]);
            float v7 = bf2f(h[(size_t)s7 * D + lane]);
            acc += v0 * w0 + v1 * w1 + v2 * w2 + v3 * w3
                 + v4 * w4 + v5 * w5 + v6 * w6 + v7 * w7;
        }
        for (; j < cnt; ++j) {
            int s = __shfl(idx, j);
            float w = __shfl(wv, j);
            acc += bf2f(h[(size_t)s * D + lane]) * w;
        }
    }
    agg[(size_t)node * D + lane] = f2bf(acc);
}

// ==================== Dense update: 8 nodes per thread, bf16 I/O =============
// hout_bf used for layers 0..3 (in-place on hb); hout_f32 for the last layer.
__global__ __launch_bounds__(256) void update_kernel(
    const u16* __restrict__ hin, const u16* __restrict__ agg,
    const float* __restrict__ Wrel, const float* __restrict__ brel,
    const float* __restrict__ Wroot, u16* __restrict__ hout_bf,
    float* __restrict__ hout_f32, int relu)
{
    __shared__ float sWrel[64 * 64];   // 16 KB
    __shared__ float sWroot[64 * 64];  // 16 KB
    __shared__ float sA[32][64];       // 8 KB
    __shared__ float sX[32][64];       // 8 KB

    const int t = threadIdx.x;
    const int nbase = blockIdx.x * 32;

    for (int i = t; i < 64 * 64; i += 256) {
        sWrel[i]  = Wrel[i];
        sWroot[i] = Wroot[i];
    }
    // Stage 32 rows of agg/hin (bf16 -> f32). 512 ushort4 chunks per array.
    for (int i = t; i < 512; i += 256) {
        int ln = i >> 4, q = i & 15;      // row, quad-of-4-dims
        int n = nbase + ln;
        ushort4 a = make_ushort4(0, 0, 0, 0), xv = make_ushort4(0, 0, 0, 0);
        if (n < N_NODES) {
            a  = ((const ushort4*)(agg + (size_t)n * D))[q];
            xv = ((const ushort4*)(hin + (size_t)n * D))[q];
        }
        int dd = q * 4;
        sA[ln][dd + 0] = bf2f(a.x);  sA[ln][dd + 1] = bf2f(a.y);
        sA[ln][dd + 2] = bf2f(a.z);  sA[ln][dd + 3] = bf2f(a.w);
        sX[ln][dd + 0] = bf2f(xv.x); sX[ln][dd + 1] = bf2f(xv.y);
        sX[ln][dd + 2] = bf2f(xv.z); sX[ln][dd + 3] = bf2f(xv.w);
    }
    __syncthreads();

    const int d = t & 63;
    const int g = t >> 6;   // wave 0..3 -> nodes g*8 .. g*8+7
    float bias = brel[d];
    float acc[8];
    #pragma unroll
    for (int j = 0; j < 8; ++j) acc[j] = bias;

    #pragma unroll 4
    for (int k4 = 0; k4 < 16; ++k4) {
        int k = k4 * 4;
        float wr0 = sWrel[(k + 0) * 64 + d];
        float wr1 = sWrel[(k + 1) * 64 + d];
        float wr2 = sWrel[(k + 2) * 64 + d];
        float wr3 = sWrel[(k + 3) * 64 + d];
        float wo0 = sWroot[(k + 0) * 64 + d];
        float wo1 = sWroot[(k + 1) * 64 + d];
        float wo2 = sWroot[(k + 2) * 64 + d];
        float wo3 = sWroot[(k + 3) * 64 + d];
        #pragma unroll
        for (int j = 0; j < 8; ++j) {
            float4 a  = ((const float4*)sA[g * 8 + j])[k4];
            float4 xv = ((const float4*)sX[g * 8 + j])[k4];
            acc[j] += a.x * wr0 + a.y * wr1 + a.z * wr2 + a.w * wr3
                    + xv.x * wo0 + xv.y * wo1 + xv.z * wo2 + xv.w * wo3;
        }
    }

    #pragma unroll
    for (int j = 0; j < 8; ++j) {
        float v = relu ? fmaxf(acc[j], 0.f) : acc[j];
        int n = nbase + g * 8 + j;
        if (n < N_NODES) {
            if (hout_f32) hout_f32[(size_t)n * D + d] = v;
            else          hout_bf [(size_t)n * D + d] = f2bf(v);
        }
    }
}

extern "C" void kernel_launch(void* const* d_in, const int* in_sizes, int n_in,
                              void* d_out, int out_size, void* d_ws, size_t ws_size,
                              hipStream_t stream)
{
    const float* x     = (const float*)d_in[0];
    const int*   ei    = (const int*)d_in[1];   // [2, E] int32
    const float* ew    = (const float*)d_in[2];
    const float* Wrel  = (const float*)d_in[3]; // [5, 64, 64]
    const float* brel  = (const float*)d_in[4]; // [5, 64]
    const float* Wroot = (const float*)d_in[5]; // [5, 64, 64]
    float* out = (float*)d_out;

    const int* src = ei;
    const int* dst = ei + N_EDGES;

    const size_t featb_bytes = (size_t)N_NODES * D * 2;  // 12.8 MB bf16
    char* ws = (char*)d_ws;
    size_t off = 0;
    u16*  hb     = (u16*)(ws + off);  off += featb_bytes;
    u16*  aggb   = (u16*)(ws + off);  off += featb_bytes;
    int*  counts = (int*)(ws + off);  off += 400000;
    int*  cursor = (int*)(ws + off);  off += 400000;
    int*  rowptr = (int*)(ws + off);  off += 400016;
    int*  bsum   = (int*)(ws + off);  off += 2048;
    int*  bscan  = (int*)(ws + off);  off += 2048;
    int2* edges  = (int2*)(ws + off); off += (size_t)N_EDGES * 8;

    const int eblocks = (N_EDGES + 255) / 256;       // 6250
    const int cblocks = (N_NODES * D / 4 + 255) / 256;
    const int ablocks = (N_NODES * 64 + 255) / 256;  // 25000 (wave per node)
    const int ublocks = (N_NODES + 31) / 32;         // 3125

    // ---- CSR build + input convert ----
    hipMemsetAsync(counts, 0, N_NODES * sizeof(int), stream);
    hist_kernel<<<eblocks, 256, 0, stream>>>(dst, counts);
    scan_bsum_kernel<<<SCAN_BLOCKS, 256, 0, stream>>>(counts, bsum);
    scan_bscan_kernel<<<1, 512, 0, stream>>>(bsum, bscan, rowptr);
    scan_final_kernel<<<SCAN_BLOCKS, 256, 0, stream>>>(counts, bscan,
                                                       rowptr, cursor);
    place_kernel<<<eblocks, 256, 0, stream>>>(src, dst, ew, cursor, edges);
    f2bf_kernel<<<cblocks, 256, 0, stream>>>(x, hb);

    // ---- 5 GraphConv layers (hb updated in place; block-local rows) ----
    for (int layer = 0; layer < N_LAYERS; ++layer) {
        agg_kernel<<<ablocks, 256, 0, stream>>>(hb, rowptr, edges, aggb);
        int last = (layer == N_LAYERS - 1);
        update_kernel<<<ublocks, 256, 0, stream>>>(
            hb, aggb, Wrel + (size_t)layer * D * D, brel + (size_t)layer * D,
            Wroot + (size_t)layer * D * D,
            last ? nullptr : hb, last ? out : nullptr,
            last ? 0 : 1);
    }
}

// Round 7
// 636.223 us; speedup vs baseline: 2.1487x; 1.2182x over previous
//
#include <hip/hip_runtime.h>

#define N_NODES 100000
#define N_EDGES 1600000
#define D 64
#define N_LAYERS 5
#define SCAN_BLOCKS 391   // ceil(N_NODES / 256)

typedef unsigned short u16;
typedef __attribute__((ext_vector_type(8))) short bf16x8;
typedef __attribute__((ext_vector_type(4))) float f32x4;

__device__ __forceinline__ float bf2f(u16 u) {
    union { unsigned int i; float f; } v;
    v.i = ((unsigned int)u) << 16;
    return v.f;
}
__device__ __forceinline__ u16 f2bf(float f) {
    union { float f; unsigned int i; } v;
    v.f = f;
    unsigned int r = v.i + 0x7FFFu + ((v.i >> 16) & 1u);  // round-nearest-even
    return (u16)(r >> 16);
}

// ============================ CSR build (once per launch) ====================

__global__ __launch_bounds__(256) void hist_kernel(
    const int* __restrict__ dst, int* __restrict__ counts)
{
    int e = blockIdx.x * 256 + threadIdx.x;
    if (e < N_EDGES) atomicAdd(&counts[dst[e]], 1);
}

__global__ __launch_bounds__(256) void scan_bsum_kernel(
    const int* __restrict__ counts, int* __restrict__ bsum)
{
    __shared__ int red[256];
    int t = threadIdx.x;
    int i = blockIdx.x * 256 + t;
    red[t] = (i < N_NODES) ? counts[i] : 0;
    __syncthreads();
    for (int off = 128; off > 0; off >>= 1) {
        if (t < off) red[t] += red[t + off];
        __syncthreads();
    }
    if (t == 0) bsum[blockIdx.x] = red[0];
}

__global__ __launch_bounds__(512) void scan_bscan_kernel(
    const int* __restrict__ bsum, int* __restrict__ bscan,
    int* __restrict__ rowptr)
{
    __shared__ int s[512];
    int t = threadIdx.x;
    int v = (t < SCAN_BLOCKS) ? bsum[t] : 0;
    s[t] = v;
    __syncthreads();
    for (int off = 1; off < 512; off <<= 1) {
        int u = (t >= off) ? s[t - off] : 0;
        __syncthreads();
        s[t] += u;
        __syncthreads();
    }
    if (t < SCAN_BLOCKS) bscan[t] = s[t] - v;
    if (t == 511) rowptr[N_NODES] = s[511];
}

__global__ __launch_bounds__(256) void scan_final_kernel(
    const int* __restrict__ counts, const int* __restrict__ bscan,
    int* __restrict__ rowptr, int* __restrict__ cursor)
{
    __shared__ int s[256];
    int t = threadIdx.x;
    int i = blockIdx.x * 256 + t;
    int v = (i < N_NODES) ? counts[i] : 0;
    s[t] = v;
    __syncthreads();
    for (int off = 1; off < 256; off <<= 1) {
        int u = (t >= off) ? s[t - off] : 0;
        __syncthreads();
        s[t] += u;
        __syncthreads();
    }
    if (i < N_NODES) {
        int excl = s[t] - v + bscan[blockIdx.x];
        rowptr[i] = excl;
        cursor[i] = excl;
    }
}

__global__ __launch_bounds__(256) void place_kernel(
    const int* __restrict__ src, const int* __restrict__ dst,
    const float* __restrict__ ew, int* __restrict__ cursor,
    int2* __restrict__ edges)
{
    int e = blockIdx.x * 256 + threadIdx.x;
    if (e >= N_EDGES) return;
    int d = dst[e];
    int p = atomicAdd(&cursor[d], 1);
    edges[p] = make_int2(src[e], __float_as_int(ew[e]));
}

// ======================= f32 -> bf16 convert (input x) =======================
__global__ __launch_bounds__(256) void f2bf_kernel(
    const float* __restrict__ in, u16* __restrict__ out)
{
    int i = blockIdx.x * 256 + threadIdx.x;   // one float4 per thread
    if (i >= (N_NODES * D) / 4) return;
    float4 v = ((const float4*)in)[i];
    ushort4 o;
    o.x = f2bf(v.x); o.y = f2bf(v.y); o.z = f2bf(v.z); o.w = f2bf(v.w);
    ((ushort4*)out)[i] = o;
}

// ================== Weight prep: W2T[l][n][k] bf16, k = [Wrel;Wroot] =========
__global__ __launch_bounds__(256) void wprep_kernel(
    const float* __restrict__ Wrel, const float* __restrict__ Wroot,
    u16* __restrict__ W2T)
{
    int i = blockIdx.x * 256 + threadIdx.x;  // over 5*64*128
    if (i >= N_LAYERS * 64 * 128) return;
    int l = i / (64 * 128);
    int rem = i % (64 * 128);
    int n = rem >> 7;   // out dim
    int k = rem & 127;  // input dim (0..63 = rel/agg, 64..127 = root/x)
    float v = (k < 64) ? Wrel[l * 4096 + k * 64 + n]
                       : Wroot[l * 4096 + (k - 64) * 64 + n];
    W2T[i] = f2bf(v);
}

// ============ Aggregation: node-per-wave, 8-deep MLP (R5-proven) =============
__global__ __launch_bounds__(256) void agg_kernel(
    const u16* __restrict__ h, const int* __restrict__ rowptr,
    const int2* __restrict__ edges, u16* __restrict__ agg)
{
    int node = (blockIdx.x * 256 + threadIdx.x) >> 6;
    int lane = threadIdx.x & 63;
    if (node >= N_NODES) return;
    int b = rowptr[node];
    int e = rowptr[node + 1];
    float acc = 0.f;
    for (int base = b; base < e; base += 64) {
        int cnt = min(64, e - base);
        int idx = 0;
        float wv = 0.f;
        if (lane < cnt) {
            int2 p = edges[base + lane];     // one coalesced 8B load
            idx = p.x;
            wv = __int_as_float(p.y);
        }
        int j = 0;
        for (; j + 8 <= cnt; j += 8) {
            int s0 = __shfl(idx, j + 0), s1 = __shfl(idx, j + 1);
            int s2 = __shfl(idx, j + 2), s3 = __shfl(idx, j + 3);
            int s4 = __shfl(idx, j + 4), s5 = __shfl(idx, j + 5);
            int s6 = __shfl(idx, j + 6), s7 = __shfl(idx, j + 7);
            float w0 = __shfl(wv, j + 0), w1 = __shfl(wv, j + 1);
            float w2 = __shfl(wv, j + 2), w3 = __shfl(wv, j + 3);
            float w4 = __shfl(wv, j + 4), w5 = __shfl(wv, j + 5);
            float w6 = __shfl(wv, j + 6), w7 = __shfl(wv, j + 7);
            float v0 = bf2f(h[(size_t)s0 * D + lane]);
            float v1 = bf2f(h[(size_t)s1 * D + lane]);
            float v2 = bf2f(h[(size_t)s2 * D + lane]);
            float v3 = bf2f(h[(size_t)s3 * D + lane]);
            float v4 = bf2f(h[(size_t)s4 * D + lane]);
            float v5 = bf2f(h[(size_t)s5 * D + lane]);
            float v6 = bf2f(h[(size_t)s6 * D + lane]);
            float v7 = bf2f(h[(size_t)s7 * D + lane]);
            acc += v0 * w0 + v1 * w1 + v2 * w2 + v3 * w3
                 + v4 * w4 + v5 * w5 + v6 * w6 + v7 * w7;
        }
        for (; j < cnt; ++j) {
            int s = __shfl(idx, j);
            float w = __shfl(wv, j);
            acc += bf2f(h[(size_t)s * D + lane]) * w;
        }
    }
    agg[(size_t)node * D + lane] = f2bf(acc);
}

// =================== Dense update via MFMA (no LDS, no barrier) ==============
// Wave = 16 nodes x 64 out-dims = 4 n-tiles x 4 k-steps of 16x16x32 bf16.
// A-frag: lane holds AX[m=lane&15][k=quad*8+j] (doc-verified). B-frag:
// lane holds W2[k=quad*8+j][n=lane&15], read from transposed W2T[n][k].
// D: col(n)=lane&15, row(m)=quad*4+reg (doc-verified). In-place safe:
// wave reads/writes only its own 16 rows; stores data-depend on all loads.
__global__ __launch_bounds__(256) void update_mfma_kernel(
    const u16* __restrict__ hin, const u16* __restrict__ agg,
    const u16* __restrict__ W2T, const float* __restrict__ brel,
    u16* __restrict__ hout_bf, float* __restrict__ hout_f32, int relu)
{
    const int wave = threadIdx.x >> 6;
    const int lane = threadIdx.x & 63;
    const int nb16 = blockIdx.x * 64 + wave * 16;
    const int m = lane & 15;   // node-in-tile for A; out-dim-in-tile for B/D
    const int q = lane >> 4;   // quad

    int anode = nb16 + m;
    size_t rowa = (size_t)((anode < N_NODES) ? anode : 0) << 6;

    bf16x8 a[4];
    a[0] = *(const bf16x8*)(agg + rowa + q * 8);        // k  0..31
    a[1] = *(const bf16x8*)(agg + rowa + 32 + q * 8);   // k 32..63
    a[2] = *(const bf16x8*)(hin + rowa + q * 8);        // k 64..95
    a[3] = *(const bf16x8*)(hin + rowa + 32 + q * 8);   // k 96..127

    bf16x8 bfr[4][4];  // [ntile][kstep]
    #pragma unroll
    for (int nt = 0; nt < 4; ++nt)
        #pragma unroll
        for (int kk = 0; kk < 4; ++kk)
            bfr[nt][kk] = *(const bf16x8*)(W2T + (size_t)(nt * 16 + m) * 128
                                           + kk * 32 + q * 8);

    f32x4 acc[4];
    #pragma unroll
    for (int nt = 0; nt < 4; ++nt) {
        float bv = brel[nt * 16 + m];
        acc[nt] = (f32x4){bv, bv, bv, bv};
    }

    #pragma unroll
    for (int kk = 0; kk < 4; ++kk)
        #pragma unroll
        for (int nt = 0; nt < 4; ++nt)
            acc[nt] = __builtin_amdgcn_mfma_f32_16x16x32_bf16(
                a[kk], bfr[nt][kk], acc[nt], 0, 0, 0);

    #pragma unroll
    for (int nt = 0; nt < 4; ++nt)
        #pragma unroll
        for (int r = 0; r < 4; ++r) {
            int n2 = nb16 + q * 4 + r;           // node (row of D)
            if (n2 < N_NODES) {
                float v = acc[nt][r];
                if (relu) v = fmaxf(v, 0.f);
                int dim = nt * 16 + m;           // out dim (col of D)
                if (hout_f32) hout_f32[(size_t)n2 * 64 + dim] = v;
                else          hout_bf [(size_t)n2 * 64 + dim] = f2bf(v);
            }
        }
}

extern "C" void kernel_launch(void* const* d_in, const int* in_sizes, int n_in,
                              void* d_out, int out_size, void* d_ws, size_t ws_size,
                              hipStream_t stream)
{
    const float* x     = (const float*)d_in[0];
    const int*   ei    = (const int*)d_in[1];   // [2, E] int32
    const float* ew    = (const float*)d_in[2];
    const float* Wrel  = (const float*)d_in[3]; // [5, 64, 64]
    const float* brel  = (const float*)d_in[4]; // [5, 64]
    const float* Wroot = (const float*)d_in[5]; // [5, 64, 64]
    float* out = (float*)d_out;

    const int* src = ei;
    const int* dst = ei + N_EDGES;

    const size_t featb_bytes = (size_t)N_NODES * D * 2;  // 12.8 MB bf16
    char* ws = (char*)d_ws;
    size_t off = 0;
    u16*  hb     = (u16*)(ws + off);  off += featb_bytes;
    u16*  aggb   = (u16*)(ws + off);  off += featb_bytes;
    u16*  W2T    = (u16*)(ws + off);  off += (size_t)N_LAYERS * 64 * 128 * 2;
    int*  counts = (int*)(ws + off);  off += 400000;
    int*  cursor = (int*)(ws + off);  off += 400000;
    int*  rowptr = (int*)(ws + off);  off += 400016;
    int*  bsum   = (int*)(ws + off);  off += 2048;
    int*  bscan  = (int*)(ws + off);  off += 2048;
    int2* edges  = (int2*)(ws + off); off += (size_t)N_EDGES * 8;

    const int eblocks = (N_EDGES + 255) / 256;       // 6250
    const int cblocks = (N_NODES * D / 4 + 255) / 256;
    const int wblocks = (N_LAYERS * 64 * 128 + 255) / 256;  // 160
    const int ablocks = (N_NODES * 64 + 255) / 256;  // 25000 (wave per node)
    const int ublocks = (N_NODES + 63) / 64;         // 1563

    // ---- CSR build + converts ----
    hipMemsetAsync(counts, 0, N_NODES * sizeof(int), stream);
    hist_kernel<<<eblocks, 256, 0, stream>>>(dst, counts);
    scan_bsum_kernel<<<SCAN_BLOCKS, 256, 0, stream>>>(counts, bsum);
    scan_bscan_kernel<<<1, 512, 0, stream>>>(bsum, bscan, rowptr);
    scan_final_kernel<<<SCAN_BLOCKS, 256, 0, stream>>>(counts, bscan,
                                                       rowptr, cursor);
    place_kernel<<<eblocks, 256, 0, stream>>>(src, dst, ew, cursor, edges);
    f2bf_kernel<<<cblocks, 256, 0, stream>>>(x, hb);
    wprep_kernel<<<wblocks, 256, 0, stream>>>(Wrel, Wroot, W2T);

    // ---- 5 GraphConv layers (hb updated in place; wave-local rows) ----
    for (int layer = 0; layer < N_LAYERS; ++layer) {
        agg_kernel<<<ablocks, 256, 0, stream>>>(hb, rowptr, edges, aggb);
        int last = (layer == N_LAYERS - 1);
        update_mfma_kernel<<<ublocks, 256, 0, stream>>>(
            hb, aggb, W2T + (size_t)layer * 64 * 128,
            brel + (size_t)layer * D,
            last ? nullptr : hb, last ? out : nullptr,
            last ? 0 : 1);
    }
}

// Round 8
// 555.404 us; speedup vs baseline: 2.4614x; 1.1455x over previous
//
#include <hip/hip_runtime.h>

#define N_NODES 100000
#define N_EDGES 1600000
#define D 64
#define N_LAYERS 5
#define SCAN_BLOCKS 391   // ceil(N_NODES / 256)

typedef unsigned short u16;
typedef __attribute__((ext_vector_type(8))) short bf16x8;
typedef __attribute__((ext_vector_type(4))) float f32x4;

__device__ __forceinline__ float bf2f(u16 u) {
    union { unsigned int i; float f; } v;
    v.i = ((unsigned int)u) << 16;
    return v.f;
}
__device__ __forceinline__ u16 f2bf(float f) {
    union { float f; unsigned int i; } v;
    v.f = f;
    unsigned int r = v.i + 0x7FFFu + ((v.i >> 16) & 1u);  // round-nearest-even
    return (u16)(r >> 16);
}
__device__ __forceinline__ float bf2f_lo(unsigned int pk) {
    union { unsigned int i; float f; } v;
    v.i = pk << 16;
    return v.f;
}
__device__ __forceinline__ float bf2f_hi(unsigned int pk) {
    union { unsigned int i; float f; } v;
    v.i = pk & 0xFFFF0000u;
    return v.f;
}

// ============================ CSR build (once per launch) ====================

__global__ __launch_bounds__(256) void hist_kernel(
    const int* __restrict__ dst, int* __restrict__ counts)
{
    int e = blockIdx.x * 256 + threadIdx.x;
    if (e < N_EDGES) atomicAdd(&counts[dst[e]], 1);
}

__global__ __launch_bounds__(256) void scan_bsum_kernel(
    const int* __restrict__ counts, int* __restrict__ bsum)
{
    __shared__ int red[256];
    int t = threadIdx.x;
    int i = blockIdx.x * 256 + t;
    red[t] = (i < N_NODES) ? counts[i] : 0;
    __syncthreads();
    for (int off = 128; off > 0; off >>= 1) {
        if (t < off) red[t] += red[t + off];
        __syncthreads();
    }
    if (t == 0) bsum[blockIdx.x] = red[0];
}

__global__ __launch_bounds__(512) void scan_bscan_kernel(
    const int* __restrict__ bsum, int* __restrict__ bscan,
    int* __restrict__ rowptr)
{
    __shared__ int s[512];
    int t = threadIdx.x;
    int v = (t < SCAN_BLOCKS) ? bsum[t] : 0;
    s[t] = v;
    __syncthreads();
    for (int off = 1; off < 512; off <<= 1) {
        int u = (t >= off) ? s[t - off] : 0;
        __syncthreads();
        s[t] += u;
        __syncthreads();
    }
    if (t < SCAN_BLOCKS) bscan[t] = s[t] - v;
    if (t == 511) rowptr[N_NODES] = s[511];
}

__global__ __launch_bounds__(256) void scan_final_kernel(
    const int* __restrict__ counts, const int* __restrict__ bscan,
    int* __restrict__ rowptr, int* __restrict__ cursor)
{
    __shared__ int s[256];
    int t = threadIdx.x;
    int i = blockIdx.x * 256 + t;
    int v = (i < N_NODES) ? counts[i] : 0;
    s[t] = v;
    __syncthreads();
    for (int off = 1; off < 256; off <<= 1) {
        int u = (t >= off) ? s[t - off] : 0;
        __syncthreads();
        s[t] += u;
        __syncthreads();
    }
    if (i < N_NODES) {
        int excl = s[t] - v + bscan[blockIdx.x];
        rowptr[i] = excl;
        cursor[i] = excl;
    }
}

__global__ __launch_bounds__(256) void place_kernel(
    const int* __restrict__ src, const int* __restrict__ dst,
    const float* __restrict__ ew, int* __restrict__ cursor,
    int2* __restrict__ edges)
{
    int e = blockIdx.x * 256 + threadIdx.x;
    if (e >= N_EDGES) return;
    int d = dst[e];
    int p = atomicAdd(&cursor[d], 1);
    edges[p] = make_int2(src[e], __float_as_int(ew[e]));
}

// ======================= f32 -> bf16 convert (input x) =======================
__global__ __launch_bounds__(256) void f2bf_kernel(
    const float* __restrict__ in, u16* __restrict__ out)
{
    int i = blockIdx.x * 256 + threadIdx.x;   // one float4 per thread
    if (i >= (N_NODES * D) / 4) return;
    float4 v = ((const float4*)in)[i];
    ushort4 o;
    o.x = f2bf(v.x); o.y = f2bf(v.y); o.z = f2bf(v.z); o.w = f2bf(v.w);
    ((ushort4*)out)[i] = o;
}

// ================== Weight prep: W2T[l][n][k] bf16, k = [Wrel;Wroot] =========
__global__ __launch_bounds__(256) void wprep_kernel(
    const float* __restrict__ Wrel, const float* __restrict__ Wroot,
    u16* __restrict__ W2T)
{
    int i = blockIdx.x * 256 + threadIdx.x;  // over 5*64*128
    if (i >= N_LAYERS * 64 * 128) return;
    int l = i / (64 * 128);
    int rem = i % (64 * 128);
    int n = rem >> 7;   // out dim
    int k = rem & 127;  // input dim (0..63 = rel/agg, 64..127 = root/x)
    float v = (k < 64) ? Wrel[l * 4096 + k * 64 + n]
                       : Wroot[l * 4096 + (k - 64) * 64 + n];
    W2T[i] = f2bf(v);
}

// ========== Aggregation: 2 nodes per wave, bf16x2 dword gather ===============
// Lanes 0-31 serve node (2*wid), lanes 32-63 node (2*wid+1). Each lane loads
// a packed bf16x2 dword (dims 2sl, 2sl+1), so ONE load instruction fetches two
// full 128B rows (256B). Halves are fully independent: own edge list, own
// trip count (exec-mask divergence only), width-32 shuffles, no butterfly.
__global__ __launch_bounds__(256) void agg_kernel(
    const u16* __restrict__ h, const int* __restrict__ rowptr,
    const int2* __restrict__ edges, u16* __restrict__ agg)
{
    int wid  = (blockIdx.x * 256 + threadIdx.x) >> 6;
    int lane = threadIdx.x & 63;
    int sl   = lane & 31;           // sublane: dim pair -> dims 2sl, 2sl+1
    int node = wid * 2 + (lane >> 5);
    if (node >= N_NODES) return;
    int b = rowptr[node];
    int e = rowptr[node + 1];
    float acc0 = 0.f, acc1 = 0.f;
    for (int base = b; base < e; base += 32) {
        int cnt = min(32, e - base);
        int idx = 0;
        float wv = 0.f;
        if (sl < cnt) {
            int2 p = edges[base + sl];   // per-half coalesced 256B segment
            idx = p.x;
            wv = __int_as_float(p.y);
        }
        int j = 0;
        for (; j + 8 <= cnt; j += 8) {
            int s0 = __shfl(idx, j + 0, 32), s1 = __shfl(idx, j + 1, 32);
            int s2 = __shfl(idx, j + 2, 32), s3 = __shfl(idx, j + 3, 32);
            int s4 = __shfl(idx, j + 4, 32), s5 = __shfl(idx, j + 5, 32);
            int s6 = __shfl(idx, j + 6, 32), s7 = __shfl(idx, j + 7, 32);
            float w0 = __shfl(wv, j + 0, 32), w1 = __shfl(wv, j + 1, 32);
            float w2 = __shfl(wv, j + 2, 32), w3 = __shfl(wv, j + 3, 32);
            float w4 = __shfl(wv, j + 4, 32), w5 = __shfl(wv, j + 5, 32);
            float w6 = __shfl(wv, j + 6, 32), w7 = __shfl(wv, j + 7, 32);
            unsigned int p0 = *(const unsigned int*)(h + ((size_t)s0 << 6) + sl * 2);
            unsigned int p1 = *(const unsigned int*)(h + ((size_t)s1 << 6) + sl * 2);
            unsigned int p2 = *(const unsigned int*)(h + ((size_t)s2 << 6) + sl * 2);
            unsigned int p3 = *(const unsigned int*)(h + ((size_t)s3 << 6) + sl * 2);
            unsigned int p4 = *(const unsigned int*)(h + ((size_t)s4 << 6) + sl * 2);
            unsigned int p5 = *(const unsigned int*)(h + ((size_t)s5 << 6) + sl * 2);
            unsigned int p6 = *(const unsigned int*)(h + ((size_t)s6 << 6) + sl * 2);
            unsigned int p7 = *(const unsigned int*)(h + ((size_t)s7 << 6) + sl * 2);
            acc0 += bf2f_lo(p0) * w0 + bf2f_lo(p1) * w1
                  + bf2f_lo(p2) * w2 + bf2f_lo(p3) * w3
                  + bf2f_lo(p4) * w4 + bf2f_lo(p5) * w5
                  + bf2f_lo(p6) * w6 + bf2f_lo(p7) * w7;
            acc1 += bf2f_hi(p0) * w0 + bf2f_hi(p1) * w1
                  + bf2f_hi(p2) * w2 + bf2f_hi(p3) * w3
                  + bf2f_hi(p4) * w4 + bf2f_hi(p5) * w5
                  + bf2f_hi(p6) * w6 + bf2f_hi(p7) * w7;
        }
        for (; j < cnt; ++j) {
            int s = __shfl(idx, j, 32);
            float w = __shfl(wv, j, 32);
            unsigned int pk = *(const unsigned int*)(h + ((size_t)s << 6) + sl * 2);
            acc0 += bf2f_lo(pk) * w;
            acc1 += bf2f_hi(pk) * w;
        }
    }
    unsigned int o = ((unsigned int)f2bf(acc1) << 16) | f2bf(acc0);
    *(unsigned int*)(agg + ((size_t)node << 6) + sl * 2) = o;
}

// =================== Dense update via MFMA (no LDS, no barrier) ==============
// Wave = 16 nodes x 64 out-dims = 4 n-tiles x 4 k-steps of 16x16x32 bf16.
// A-frag: lane holds AX[m=lane&15][k=quad*8+j] (doc-verified). B-frag:
// lane holds W2[k=quad*8+j][n=lane&15], read from transposed W2T[n][k].
// D: col(n)=lane&15, row(m)=quad*4+reg (doc-verified). In-place safe:
// wave reads/writes only its own 16 rows; stores data-depend on all loads.
__global__ __launch_bounds__(256) void update_mfma_kernel(
    const u16* __restrict__ hin, const u16* __restrict__ agg,
    const u16* __restrict__ W2T, const float* __restrict__ brel,
    u16* __restrict__ hout_bf, float* __restrict__ hout_f32, int relu)
{
    const int wave = threadIdx.x >> 6;
    const int lane = threadIdx.x & 63;
    const int nb16 = blockIdx.x * 64 + wave * 16;
    const int m = lane & 15;   // node-in-tile for A; out-dim-in-tile for B/D
    const int q = lane >> 4;   // quad

    int anode = nb16 + m;
    size_t rowa = (size_t)((anode < N_NODES) ? anode : 0) << 6;

    bf16x8 a[4];
    a[0] = *(const bf16x8*)(agg + rowa + q * 8);        // k  0..31
    a[1] = *(const bf16x8*)(agg + rowa + 32 + q * 8);   // k 32..63
    a[2] = *(const bf16x8*)(hin + rowa + q * 8);        // k 64..95
    a[3] = *(const bf16x8*)(hin + rowa + 32 + q * 8);   // k 96..127

    bf16x8 bfr[4][4];  // [ntile][kstep]
    #pragma unroll
    for (int nt = 0; nt < 4; ++nt)
        #pragma unroll
        for (int kk = 0; kk < 4; ++kk)
            bfr[nt][kk] = *(const bf16x8*)(W2T + (size_t)(nt * 16 + m) * 128
                                           + kk * 32 + q * 8);

    f32x4 acc[4];
    #pragma unroll
    for (int nt = 0; nt < 4; ++nt) {
        float bv = brel[nt * 16 + m];
        acc[nt] = (f32x4){bv, bv, bv, bv};
    }

    #pragma unroll
    for (int kk = 0; kk < 4; ++kk)
        #pragma unroll
        for (int nt = 0; nt < 4; ++nt)
            acc[nt] = __builtin_amdgcn_mfma_f32_16x16x32_bf16(
                a[kk], bfr[nt][kk], acc[nt], 0, 0, 0);

    #pragma unroll
    for (int nt = 0; nt < 4; ++nt)
        #pragma unroll
        for (int r = 0; r < 4; ++r) {
            int n2 = nb16 + q * 4 + r;           // node (row of D)
            if (n2 < N_NODES) {
                float v = acc[nt][r];
                if (relu) v = fmaxf(v, 0.f);
                int dim = nt * 16 + m;           // out dim (col of D)
                if (hout_f32) hout_f32[(size_t)n2 * 64 + dim] = v;
                else          hout_bf [(size_t)n2 * 64 + dim] = f2bf(v);
            }
        }
}

extern "C" void kernel_launch(void* const* d_in, const int* in_sizes, int n_in,
                              void* d_out, int out_size, void* d_ws, size_t ws_size,
                              hipStream_t stream)
{
    const float* x     = (const float*)d_in[0];
    const int*   ei    = (const int*)d_in[1];   // [2, E] int32
    const float* ew    = (const float*)d_in[2];
    const float* Wrel  = (const float*)d_in[3]; // [5, 64, 64]
    const float* brel  = (const float*)d_in[4]; // [5, 64]
    const float* Wroot = (const float*)d_in[5]; // [5, 64, 64]
    float* out = (float*)d_out;

    const int* src = ei;
    const int* dst = ei + N_EDGES;

    const size_t featb_bytes = (size_t)N_NODES * D * 2;  // 12.8 MB bf16
    char* ws = (char*)d_ws;
    size_t off = 0;
    u16*  hb     = (u16*)(ws + off);  off += featb_bytes;
    u16*  aggb   = (u16*)(ws + off);  off += featb_bytes;
    u16*  W2T    = (u16*)(ws + off);  off += (size_t)N_LAYERS * 64 * 128 * 2;
    int*  counts = (int*)(ws + off);  off += 400000;
    int*  cursor = (int*)(ws + off);  off += 400000;
    int*  rowptr = (int*)(ws + off);  off += 400016;
    int*  bsum   = (int*)(ws + off);  off += 2048;
    int*  bscan  = (int*)(ws + off);  off += 2048;
    int2* edges  = (int2*)(ws + off); off += (size_t)N_EDGES * 8;

    const int eblocks = (N_EDGES + 255) / 256;       // 6250
    const int cblocks = (N_NODES * D / 4 + 255) / 256;
    const int wblocks = (N_LAYERS * 64 * 128 + 255) / 256;  // 160
    const int ablocks = ((N_NODES + 1) / 2 + 3) / 4; // 12500 (2 nodes/wave)
    const int ublocks = (N_NODES + 63) / 64;         // 1563

    // ---- CSR build + converts ----
    hipMemsetAsync(counts, 0, N_NODES * sizeof(int), stream);
    hist_kernel<<<eblocks, 256, 0, stream>>>(dst, counts);
    scan_bsum_kernel<<<SCAN_BLOCKS, 256, 0, stream>>>(counts, bsum);
    scan_bscan_kernel<<<1, 512, 0, stream>>>(bsum, bscan, rowptr);
    scan_final_kernel<<<SCAN_BLOCKS, 256, 0, stream>>>(counts, bscan,
                                                       rowptr, cursor);
    place_kernel<<<eblocks, 256, 0, stream>>>(src, dst, ew, cursor, edges);
    f2bf_kernel<<<cblocks, 256, 0, stream>>>(x, hb);
    wprep_kernel<<<wblocks, 256, 0, stream>>>(Wrel, Wroot, W2T);

    // ---- 5 GraphConv layers (hb updated in place; wave-local rows) ----
    for (int layer = 0; layer < N_LAYERS; ++layer) {
        agg_kernel<<<ablocks, 256, 0, stream>>>(hb, rowptr, edges, aggb);
        int last = (layer == N_LAYERS - 1);
        update_mfma_kernel<<<ublocks, 256, 0, stream>>>(
            hb, aggb, W2T + (size_t)layer * 64 * 128,
            brel + (size_t)layer * D,
            last ? nullptr : hb, last ? out : nullptr,
            last ? 0 : 1);
    }
}

// Round 9
// 517.470 us; speedup vs baseline: 2.6418x; 1.0733x over previous
//
#include <hip/hip_runtime.h>

#define N_NODES 100000
#define N_EDGES 1600000
#define D 64
#define N_LAYERS 5
#define SCAN_BLOCKS 391   // ceil(N_NODES / 256)

typedef unsigned short u16;
typedef __attribute__((ext_vector_type(8))) short bf16x8;
typedef __attribute__((ext_vector_type(4))) float f32x4;

__device__ __forceinline__ float bf2f(u16 u) {
    union { unsigned int i; float f; } v;
    v.i = ((unsigned int)u) << 16;
    return v.f;
}
__device__ __forceinline__ u16 f2bf(float f) {
    union { float f; unsigned int i; } v;
    v.f = f;
    unsigned int r = v.i + 0x7FFFu + ((v.i >> 16) & 1u);  // round-nearest-even
    return (u16)(r >> 16);
}
__device__ __forceinline__ float bf2f_lo(unsigned int pk) {
    union { unsigned int i; float f; } v;
    v.i = pk << 16;
    return v.f;
}
__device__ __forceinline__ float bf2f_hi(unsigned int pk) {
    union { unsigned int i; float f; } v;
    v.i = pk & 0xFFFF0000u;
    return v.f;
}

// ============================ CSR build (once per launch) ====================

__global__ __launch_bounds__(256) void hist_kernel(
    const int* __restrict__ dst, int* __restrict__ counts)
{
    int e = blockIdx.x * 256 + threadIdx.x;
    if (e < N_EDGES) atomicAdd(&counts[dst[e]], 1);
}

__global__ __launch_bounds__(256) void scan_bsum_kernel(
    const int* __restrict__ counts, int* __restrict__ bsum)
{
    __shared__ int red[256];
    int t = threadIdx.x;
    int i = blockIdx.x * 256 + t;
    red[t] = (i < N_NODES) ? counts[i] : 0;
    __syncthreads();
    for (int off = 128; off > 0; off >>= 1) {
        if (t < off) red[t] += red[t + off];
        __syncthreads();
    }
    if (t == 0) bsum[blockIdx.x] = red[0];
}

__global__ __launch_bounds__(512) void scan_bscan_kernel(
    const int* __restrict__ bsum, int* __restrict__ bscan,
    int* __restrict__ rowptr)
{
    __shared__ int s[512];
    int t = threadIdx.x;
    int v = (t < SCAN_BLOCKS) ? bsum[t] : 0;
    s[t] = v;
    __syncthreads();
    for (int off = 1; off < 512; off <<= 1) {
        int u = (t >= off) ? s[t - off] : 0;
        __syncthreads();
        s[t] += u;
        __syncthreads();
    }
    if (t < SCAN_BLOCKS) bscan[t] = s[t] - v;
    if (t == 511) rowptr[N_NODES] = s[511];
}

__global__ __launch_bounds__(256) void scan_final_kernel(
    const int* __restrict__ counts, const int* __restrict__ bscan,
    int* __restrict__ rowptr, int* __restrict__ cursor)
{
    __shared__ int s[256];
    int t = threadIdx.x;
    int i = blockIdx.x * 256 + t;
    int v = (i < N_NODES) ? counts[i] : 0;
    s[t] = v;
    __syncthreads();
    for (int off = 1; off < 256; off <<= 1) {
        int u = (t >= off) ? s[t - off] : 0;
        __syncthreads();
        s[t] += u;
        __syncthreads();
    }
    if (i < N_NODES) {
        int excl = s[t] - v + bscan[blockIdx.x];
        rowptr[i] = excl;
        cursor[i] = excl;
    }
}

// ============ Placement, XCD-partitioned for write-sector locality ===========
// Node space split into 8 regions of 12500; block (blockIdx%8 == x) handles
// only dst in region x. With gfx950's round-robin blockIdx->XCD dispatch, all
// stores to a given edges[] sector then come from ONE XCD: its L2 merges the
// 8 edges/sector and the 1.6MB region stays resident (vs 64B writeback per
// 8B store when sectors were shared across XCDs). Mapping is a speed-only
// heuristic; correctness holds regardless. dst read 8x (coalesced, cheap).
__global__ __launch_bounds__(256) void place_kernel(
    const int* __restrict__ src, const int* __restrict__ dst,
    const float* __restrict__ ew, int* __restrict__ cursor,
    int2* __restrict__ edges)
{
    const int x  = blockIdx.x & 7;    // region / intended XCD
    const int ci = blockIdx.x >> 3;   // edge chunk
    const int xlo = x * 12500, xhi = xlo + 12500;   // 100000 = 8 * 12500
    const int e0 = ci * 12500;                      // 1.6M = 128 * 12500
    const int e1 = e0 + 12500;
    for (int e = e0 + threadIdx.x; e < e1; e += 256) {
        int d = dst[e];
        if (d >= xlo && d < xhi) {
            int p = atomicAdd(&cursor[d], 1);
            edges[p] = make_int2(src[e], __float_as_int(ew[e]));
        }
    }
}

// ======================= f32 -> bf16 convert (input x) =======================
__global__ __launch_bounds__(256) void f2bf_kernel(
    const float* __restrict__ in, u16* __restrict__ out)
{
    int i = blockIdx.x * 256 + threadIdx.x;   // one float4 per thread
    if (i >= (N_NODES * D) / 4) return;
    float4 v = ((const float4*)in)[i];
    ushort4 o;
    o.x = f2bf(v.x); o.y = f2bf(v.y); o.z = f2bf(v.z); o.w = f2bf(v.w);
    ((ushort4*)out)[i] = o;
}

// ================== Weight prep: W2T[l][n][k] bf16, k = [Wrel;Wroot] =========
__global__ __launch_bounds__(256) void wprep_kernel(
    const float* __restrict__ Wrel, const float* __restrict__ Wroot,
    u16* __restrict__ W2T)
{
    int i = blockIdx.x * 256 + threadIdx.x;  // over 5*64*128
    if (i >= N_LAYERS * 64 * 128) return;
    int l = i / (64 * 128);
    int rem = i % (64 * 128);
    int n = rem >> 7;   // out dim
    int k = rem & 127;  // input dim (0..63 = rel/agg, 64..127 = root/x)
    float v = (k < 64) ? Wrel[l * 4096 + k * 64 + n]
                       : Wroot[l * 4096 + (k - 64) * 64 + n];
    W2T[i] = f2bf(v);
}

// ========== Aggregation: 2 nodes per wave, bf16x2 dword gather ===============
// Lanes 0-31 serve node (2*wid), lanes 32-63 node (2*wid+1). Each lane loads
// a packed bf16x2 dword (dims 2sl, 2sl+1), so ONE load instruction fetches two
// full 128B rows (256B). Halves are fully independent: own edge list, own
// trip count (exec-mask divergence only), width-32 shuffles, no butterfly.
__global__ __launch_bounds__(256) void agg_kernel(
    const u16* __restrict__ h, const int* __restrict__ rowptr,
    const int2* __restrict__ edges, u16* __restrict__ agg)
{
    int wid  = (blockIdx.x * 256 + threadIdx.x) >> 6;
    int lane = threadIdx.x & 63;
    int sl   = lane & 31;           // sublane: dim pair -> dims 2sl, 2sl+1
    int node = wid * 2 + (lane >> 5);
    if (node >= N_NODES) return;
    int b = rowptr[node];
    int e = rowptr[node + 1];
    float acc0 = 0.f, acc1 = 0.f;
    for (int base = b; base < e; base += 32) {
        int cnt = min(32, e - base);
        int idx = 0;
        float wv = 0.f;
        if (sl < cnt) {
            int2 p = edges[base + sl];   // per-half coalesced 256B segment
            idx = p.x;
            wv = __int_as_float(p.y);
        }
        int j = 0;
        for (; j + 8 <= cnt; j += 8) {
            int s0 = __shfl(idx, j + 0, 32), s1 = __shfl(idx, j + 1, 32);
            int s2 = __shfl(idx, j + 2, 32), s3 = __shfl(idx, j + 3, 32);
            int s4 = __shfl(idx, j + 4, 32), s5 = __shfl(idx, j + 5, 32);
            int s6 = __shfl(idx, j + 6, 32), s7 = __shfl(idx, j + 7, 32);
            float w0 = __shfl(wv, j + 0, 32), w1 = __shfl(wv, j + 1, 32);
            float w2 = __shfl(wv, j + 2, 32), w3 = __shfl(wv, j + 3, 32);
            float w4 = __shfl(wv, j + 4, 32), w5 = __shfl(wv, j + 5, 32);
            float w6 = __shfl(wv, j + 6, 32), w7 = __shfl(wv, j + 7, 32);
            unsigned int p0 = *(const unsigned int*)(h + ((size_t)s0 << 6) + sl * 2);
            unsigned int p1 = *(const unsigned int*)(h + ((size_t)s1 << 6) + sl * 2);
            unsigned int p2 = *(const unsigned int*)(h + ((size_t)s2 << 6) + sl * 2);
            unsigned int p3 = *(const unsigned int*)(h + ((size_t)s3 << 6) + sl * 2);
            unsigned int p4 = *(const unsigned int*)(h + ((size_t)s4 << 6) + sl * 2);
            unsigned int p5 = *(const unsigned int*)(h + ((size_t)s5 << 6) + sl * 2);
            unsigned int p6 = *(const unsigned int*)(h + ((size_t)s6 << 6) + sl * 2);
            unsigned int p7 = *(const unsigned int*)(h + ((size_t)s7 << 6) + sl * 2);
            acc0 += bf2f_lo(p0) * w0 + bf2f_lo(p1) * w1
                  + bf2f_lo(p2) * w2 + bf2f_lo(p3) * w3
                  + bf2f_lo(p4) * w4 + bf2f_lo(p5) * w5
                  + bf2f_lo(p6) * w6 + bf2f_lo(p7) * w7;
            acc1 += bf2f_hi(p0) * w0 + bf2f_hi(p1) * w1
                  + bf2f_hi(p2) * w2 + bf2f_hi(p3) * w3
                  + bf2f_hi(p4) * w4 + bf2f_hi(p5) * w5
                  + bf2f_hi(p6) * w6 + bf2f_hi(p7) * w7;
        }
        for (; j < cnt; ++j) {
            int s = __shfl(idx, j, 32);
            float w = __shfl(wv, j, 32);
            unsigned int pk = *(const unsigned int*)(h + ((size_t)s << 6) + sl * 2);
            acc0 += bf2f_lo(pk) * w;
            acc1 += bf2f_hi(pk) * w;
        }
    }
    unsigned int o = ((unsigned int)f2bf(acc1) << 16) | f2bf(acc0);
    *(unsigned int*)(agg + ((size_t)node << 6) + sl * 2) = o;
}

// =================== Dense update via MFMA (no LDS, no barrier) ==============
// Wave = 16 nodes x 64 out-dims = 4 n-tiles x 4 k-steps of 16x16x32 bf16.
// A-frag: lane holds AX[m=lane&15][k=quad*8+j] (doc-verified). B-frag:
// lane holds W2[k=quad*8+j][n=lane&15], read from transposed W2T[n][k].
// D: col(n)=lane&15, row(m)=quad*4+reg (doc-verified). In-place safe:
// wave reads/writes only its own 16 rows; stores data-depend on all loads.
__global__ __launch_bounds__(256) void update_mfma_kernel(
    const u16* __restrict__ hin, const u16* __restrict__ agg,
    const u16* __restrict__ W2T, const float* __restrict__ brel,
    u16* __restrict__ hout_bf, float* __restrict__ hout_f32, int relu)
{
    const int wave = threadIdx.x >> 6;
    const int lane = threadIdx.x & 63;
    const int nb16 = blockIdx.x * 64 + wave * 16;
    const int m = lane & 15;   // node-in-tile for A; out-dim-in-tile for B/D
    const int q = lane >> 4;   // quad

    int anode = nb16 + m;
    size_t rowa = (size_t)((anode < N_NODES) ? anode : 0) << 6;

    bf16x8 a[4];
    a[0] = *(const bf16x8*)(agg + rowa + q * 8);        // k  0..31
    a[1] = *(const bf16x8*)(agg + rowa + 32 + q * 8);   // k 32..63
    a[2] = *(const bf16x8*)(hin + rowa + q * 8);        // k 64..95
    a[3] = *(const bf16x8*)(hin + rowa + 32 + q * 8);   // k 96..127

    bf16x8 bfr[4][4];  // [ntile][kstep]
    #pragma unroll
    for (int nt = 0; nt < 4; ++nt)
        #pragma unroll
        for (int kk = 0; kk < 4; ++kk)
            bfr[nt][kk] = *(const bf16x8*)(W2T + (size_t)(nt * 16 + m) * 128
                                           + kk * 32 + q * 8);

    f32x4 acc[4];
    #pragma unroll
    for (int nt = 0; nt < 4; ++nt) {
        float bv = brel[nt * 16 + m];
        acc[nt] = (f32x4){bv, bv, bv, bv};
    }

    #pragma unroll
    for (int kk = 0; kk < 4; ++kk)
        #pragma unroll
        for (int nt = 0; nt < 4; ++nt)
            acc[nt] = __builtin_amdgcn_mfma_f32_16x16x32_bf16(
                a[kk], bfr[nt][kk], acc[nt], 0, 0, 0);

    #pragma unroll
    for (int nt = 0; nt < 4; ++nt)
        #pragma unroll
        for (int r = 0; r < 4; ++r) {
            int n2 = nb16 + q * 4 + r;           // node (row of D)
            if (n2 < N_NODES) {
                float v = acc[nt][r];
                if (relu) v = fmaxf(v, 0.f);
                int dim = nt * 16 + m;           // out dim (col of D)
                if (hout_f32) hout_f32[(size_t)n2 * 64 + dim] = v;
                else          hout_bf [(size_t)n2 * 64 + dim] = f2bf(v);
            }
        }
}

extern "C" void kernel_launch(void* const* d_in, const int* in_sizes, int n_in,
                              void* d_out, int out_size, void* d_ws, size_t ws_size,
                              hipStream_t stream)
{
    const float* x     = (const float*)d_in[0];
    const int*   ei    = (const int*)d_in[1];   // [2, E] int32
    const float* ew    = (const float*)d_in[2];
    const float* Wrel  = (const float*)d_in[3]; // [5, 64, 64]
    const float* brel  = (const float*)d_in[4]; // [5, 64]
    const float* Wroot = (const float*)d_in[5]; // [5, 64, 64]
    float* out = (float*)d_out;

    const int* src = ei;
    const int* dst = ei + N_EDGES;

    const size_t featb_bytes = (size_t)N_NODES * D * 2;  // 12.8 MB bf16
    char* ws = (char*)d_ws;
    size_t off = 0;
    u16*  hb     = (u16*)(ws + off);  off += featb_bytes;
    u16*  aggb   = (u16*)(ws + off);  off += featb_bytes;
    u16*  W2T    = (u16*)(ws + off);  off += (size_t)N_LAYERS * 64 * 128 * 2;
    int*  counts = (int*)(ws + off);  off += 400000;
    int*  cursor = (int*)(ws + off);  off += 400000;
    int*  rowptr = (int*)(ws + off);  off += 400016;
    int*  bsum   = (int*)(ws + off);  off += 2048;
    int*  bscan  = (int*)(ws + off);  off += 2048;
    int2* edges  = (int2*)(ws + off); off += (size_t)N_EDGES * 8;

    const int eblocks = (N_EDGES + 255) / 256;       // 6250
    const int pblocks = 8 * 128;                     // 8 regions x 128 chunks
    const int cblocks = (N_NODES * D / 4 + 255) / 256;
    const int wblocks = (N_LAYERS * 64 * 128 + 255) / 256;  // 160
    const int ablocks = ((N_NODES + 1) / 2 + 3) / 4; // 12500 (2 nodes/wave)
    const int ublocks = (N_NODES + 63) / 64;         // 1563

    // ---- CSR build + converts ----
    hipMemsetAsync(counts, 0, N_NODES * sizeof(int), stream);
    hist_kernel<<<eblocks, 256, 0, stream>>>(dst, counts);
    scan_bsum_kernel<<<SCAN_BLOCKS, 256, 0, stream>>>(counts, bsum);
    scan_bscan_kernel<<<1, 512, 0, stream>>>(bsum, bscan, rowptr);
    scan_final_kernel<<<SCAN_BLOCKS, 256, 0, stream>>>(counts, bscan,
                                                       rowptr, cursor);
    place_kernel<<<pblocks, 256, 0, stream>>>(src, dst, ew, cursor, edges);
    f2bf_kernel<<<cblocks, 256, 0, stream>>>(x, hb);
    wprep_kernel<<<wblocks, 256, 0, stream>>>(Wrel, Wroot, W2T);

    // ---- 5 GraphConv layers (hb updated in place; wave-local rows) ----
    for (int layer = 0; layer < N_LAYERS; ++layer) {
        agg_kernel<<<ablocks, 256, 0, stream>>>(hb, rowptr, edges, aggb);
        int last = (layer == N_LAYERS - 1);
        update_mfma_kernel<<<ublocks, 256, 0, stream>>>(
            hb, aggb, W2T + (size_t)layer * 64 * 128,
            brel + (size_t)layer * D,
            last ? nullptr : hb, last ? out : nullptr,
            last ? 0 : 1);
    }
}